// Round 12
// baseline (960.449 us; speedup 1.0000x reference)
//
#include <hip/hip_runtime.h>
#include <hip/hip_bf16.h>
#include <cstdint>

// ---------------------------------------------------------------------------
// SelfAttention fused block: B=4, S=2048, D=1024, fp32 in/out.
// R8: occupancy fix. BK=32 everywhere -> gemm256 LDS 64 KB, tn128 LDS 72 KB
// -> 2 blocks/CU (was 1): cross-block overlap fills barrier stalls that were
// 54% of cycles. Same wait ledgers scaled (WAITV(2) 4-phase / WAITV(3) coarse).
// Dispatches (all GEMMs 256 blocks = 1.0 round):
//   QKV_A  gemm256 (32x8):  Q,K
//   Vproj  tn128<VOUT> (4x64): Vt[d][(b,s)] via operand swap
//   scores gemm256 (8x8x4)
//   PV     tn128 (8x8x4)
//   WoGLU_A gemm256+Asel (32x8): [T1 | Gval]
//   WoGLU_B tn128 (32x8): Ggate
// ---------------------------------------------------------------------------

typedef __bf16 bf16x8 __attribute__((ext_vector_type(8)));
typedef __bf16 bf16x4 __attribute__((ext_vector_type(4)));
typedef float f32x4 __attribute__((ext_vector_type(4)));

#define SYNC() do { asm volatile("" ::: "memory"); __builtin_amdgcn_s_barrier(); asm volatile("" ::: "memory"); } while (0)
#define WAITV(n) asm volatile("s_waitcnt vmcnt(" #n ")" ::: "memory")

__device__ __forceinline__ void gload_lds16(const void* g, void* l) {
    __builtin_amdgcn_global_load_lds(
        (__attribute__((address_space(1))) void*)(uintptr_t)g,
        (__attribute__((address_space(3))) void*)(uintptr_t)l,
        16, 0, 0);
}

// ---------------------------------------------------------------------------
// gemm256: C[m,n] = sum_k A[m,k] * Bt[n,k].  Tile 256x256, BK=32, 8 waves,
// 2-buf LDS 64 KB -> 2 blocks/CU. 4 phases/K-tile, counted WAITV(2) at
// phases 1,2,4. LDS rows 64 B = 4 slots; swizzle slot^(row&3) both-sides.
// EPI 0: bf16 = acc + bias; EPI 1: bf16 = acc * scale.
// A-select: blockIdx.y*256 >= nsplit -> A2/lda2.
// Ledger (stage order per tile: A0,B0,B1,A1; 1 load/thread each):
//   P1 stages A0[t+1], WAITV(2) completes B1[t]; P2 stages B0[t+1], WAITV(2)
//   completes A1[t]; P3 stages B1[t+1]; P4 stages A1[t+1], WAITV(2)
//   completes A0,B0[t+1]. Peel: WAITV(1) then WAITV(0).
// ---------------------------------------------------------------------------
template <int EPI>
__global__ __launch_bounds__(512, 4) void gemm256(
    const __hip_bfloat16* __restrict__ A1, int lda1,
    const __hip_bfloat16* __restrict__ A2, int lda2, int nsplit,
    const __hip_bfloat16* __restrict__ Bt,
    __hip_bfloat16* __restrict__ Cout, const float* __restrict__ bias, float scale,
    int K, int ldb, int ldc,
    long strideA, long strideB, long strideC)
{
    __shared__ __align__(16) char smem[65536];   // 2 bufs x 32 KB

    const int b = blockIdx.z;
    const int tid = threadIdx.x;
    const int lane = tid & 63;
    const int wm = (tid >> 6) & 1;
    const int wn = (tid >> 6) >> 1;

    const bool sel2 = ((int)blockIdx.y * 256) >= nsplit;
    const __hip_bfloat16* A = sel2 ? A2 : A1;
    const int lda = sel2 ? lda2 : lda1;

    const __hip_bfloat16* gA = A + (long)b * strideA + (long)blockIdx.x * 256 * lda;
    const __hip_bfloat16* gB = Bt + (long)b * strideB + (long)blockIdx.y * 256 * ldb;

    const int r0 = tid >> 2;                 // 0..127 (row within 128-row half)
    const int s0 = (tid & 3) ^ (r0 & 3);     // inverse-swizzled 16B slot (4/row)

    // 1 load/thread: half-tile = 128 rows x 32 cols x 2B = 8 KB
#define STAGE(buf, isB, half, kt)                                                        \
    do {                                                                                 \
        const __hip_bfloat16* g_ = (isB) ? gB : gA;                                      \
        const int ld_ = (isB) ? ldb : lda;                                               \
        char* l_ = smem + (buf) * 32768 + (isB) * 16384 + (half) * 8192;                 \
        gload_lds16(g_ + (long)((half) * 128 + r0) * ld_ + (kt) * 32 + s0 * 8, l_ + tid * 16); \
    } while (0)

    const int fr = lane & 15;
    const int kg3 = lane >> 4;   // 16B k-slot this lane's fragment wants (0..3)

#define LDA_(dst, buf, mh, mi)                                                           \
    do {                                                                                 \
        const int lr_ = wm * 64 + (mi) * 16 + fr;                                        \
        const int sl_ = kg3 ^ (lr_ & 3);                                                 \
        dst = *(const bf16x8*)(smem + (buf) * 32768 + (mh) * 8192 + lr_ * 64 + sl_ * 16); \
    } while (0)
#define LDB_(dst, buf, nh, ni)                                                           \
    do {                                                                                 \
        const int lr_ = wn * 32 + (ni) * 16 + fr;                                        \
        const int sl_ = kg3 ^ (lr_ & 3);                                                 \
        dst = *(const bf16x8*)(smem + (buf) * 32768 + 16384 + (nh) * 8192 + lr_ * 64 + sl_ * 16); \
    } while (0)

    f32x4 acc[2][2][4][2];
#pragma unroll
    for (int mh = 0; mh < 2; ++mh)
#pragma unroll
        for (int nh = 0; nh < 2; ++nh)
#pragma unroll
            for (int mi = 0; mi < 4; ++mi)
#pragma unroll
                for (int ni = 0; ni < 2; ++ni) acc[mh][nh][mi][ni] = {0.f, 0.f, 0.f, 0.f};

    bf16x8 av[4], bv[2];

#define MFMA_QUAD(mh, nh)                                                                \
    do {                                                                                 \
        __builtin_amdgcn_s_setprio(1);                                                   \
        _Pragma("unroll")                                                                \
        for (int mi = 0; mi < 4; ++mi)                                                   \
            _Pragma("unroll")                                                            \
            for (int ni = 0; ni < 2; ++ni)                                               \
                acc[mh][nh][mi][ni] = __builtin_amdgcn_mfma_f32_16x16x32_bf16(           \
                    av[mi], bv[ni], acc[mh][nh][mi][ni], 0, 0, 0);                       \
        __builtin_amdgcn_s_setprio(0);                                                   \
    } while (0)

    const int NT = K >> 5;

    // prologue: stage tile 0 in wait-order A0,B0,B1,A1
    STAGE(0, 0, 0, 0);
    STAGE(0, 1, 0, 0);
    STAGE(0, 1, 1, 0);
    STAGE(0, 0, 1, 0);
    WAITV(2);
    SYNC();

    for (int t = 0; t < NT - 1; ++t) {
        const int c = t & 1;
#pragma unroll
        for (int mi = 0; mi < 4; ++mi) LDA_(av[mi], c, 0, mi);
#pragma unroll
        for (int ni = 0; ni < 2; ++ni) LDB_(bv[ni], c, 0, ni);
        STAGE(c ^ 1, 0, 0, t + 1);
        MFMA_QUAD(0, 0);
        WAITV(2);
        SYNC();
#pragma unroll
        for (int ni = 0; ni < 2; ++ni) LDB_(bv[ni], c, 1, ni);
        STAGE(c ^ 1, 1, 0, t + 1);
        MFMA_QUAD(0, 1);
        WAITV(2);
        SYNC();
#pragma unroll
        for (int mi = 0; mi < 4; ++mi) LDA_(av[mi], c, 1, mi);
        STAGE(c ^ 1, 1, 1, t + 1);
        MFMA_QUAD(1, 1);
        SYNC();
#pragma unroll
        for (int ni = 0; ni < 2; ++ni) LDB_(bv[ni], c, 0, ni);
        STAGE(c ^ 1, 0, 1, t + 1);
        MFMA_QUAD(1, 0);
        WAITV(2);
        SYNC();
    }

    {   // peeled last tile
        const int c = (NT - 1) & 1;
#pragma unroll
        for (int mi = 0; mi < 4; ++mi) LDA_(av[mi], c, 0, mi);
#pragma unroll
        for (int ni = 0; ni < 2; ++ni) LDB_(bv[ni], c, 0, ni);
        MFMA_QUAD(0, 0);
        WAITV(1);
        SYNC();
#pragma unroll
        for (int ni = 0; ni < 2; ++ni) LDB_(bv[ni], c, 1, ni);
        MFMA_QUAD(0, 1);
        WAITV(0);
        SYNC();
#pragma unroll
        for (int mi = 0; mi < 4; ++mi) LDA_(av[mi], c, 1, mi);
        MFMA_QUAD(1, 1);
#pragma unroll
        for (int ni = 0; ni < 2; ++ni) LDB_(bv[ni], c, 0, ni);
        MFMA_QUAD(1, 0);
    }

    // epilogue: frag C/D layout: col = lane&15, row = (lane>>4)*4 + i
    const long row0 = (long)blockIdx.x * 256 + wm * 64 + (lane >> 4) * 4;
    const long col0 = (long)blockIdx.y * 256 + wn * 32 + (lane & 15);
#pragma unroll
    for (int mh = 0; mh < 2; ++mh) {
#pragma unroll
        for (int nh = 0; nh < 2; ++nh) {
#pragma unroll
            for (int ni = 0; ni < 2; ++ni) {
                const long col = col0 + nh * 128 + ni * 16;
                const float bval = (EPI == 0 && bias != nullptr) ? bias[col] : 0.f;
#pragma unroll
                for (int mi = 0; mi < 4; ++mi) {
                    const long row = row0 + mh * 128 + mi * 16;
#pragma unroll
                    for (int i = 0; i < 4; ++i) {
                        const float v = (EPI == 1) ? acc[mh][nh][mi][ni][i] * scale
                                                   : acc[mh][nh][mi][ni][i] + bval;
                        Cout[(long)b * strideC + (row + i) * (long)ldc + col] = __float2bfloat16(v);
                    }
                }
            }
        }
    }
#undef STAGE
#undef LDA_
#undef LDB_
#undef MFMA_QUAD
}

// ---------------------------------------------------------------------------
// gemm_tn128: 256x128, BK=32, 3-buf x 24 KB = 72 KB -> 2 blocks/CU.
// Coarse 1-barrier loop (R3-proven), stage t+2 during t (3 loads/thread),
// boundary WAITV(3) completes tile t+1.
// VOUT=0: C[b][row*ldc+col] = acc + bias[col] (bf16).
// VOUT=1: rows are d, global cols are (b,s): vt[b][d][s] = acc + bias[row].
// ---------------------------------------------------------------------------
template <int VOUT>
__global__ __launch_bounds__(512, 4) void gemm_tn128(
    const __hip_bfloat16* __restrict__ A, int lda,
    const __hip_bfloat16* __restrict__ Bt,
    __hip_bfloat16* __restrict__ Cout, const float* __restrict__ bias,
    __hip_bfloat16* __restrict__ vt,
    int K, int ldb, int ldc,
    long strideA, long strideB, long strideC)
{
    __shared__ __align__(16) char smem[73728];   // 3 x 24576 (A 16 KB | B 8 KB)

    const int b = blockIdx.z;
    const int tid = threadIdx.x;
    const int lane = tid & 63;
    const int wid = tid >> 6;
    const int wm = wid & 3;
    const int wn = wid >> 2;

    const __hip_bfloat16* gA = A + (long)b * strideA + (long)blockIdx.x * 256 * lda;
    const __hip_bfloat16* gB = Bt + (long)b * strideB + (long)blockIdx.y * 128 * ldb;

    const int r0 = tid >> 2;                 // 0..127
    const int s0 = (tid & 3) ^ (r0 & 3);

#define STG_A(base_, kt_)                                                                          \
    do {                                                                                           \
        gload_lds16(gA + (long)r0 * lda + (kt_) * 32 + s0 * 8, (base_) + tid * 16);                \
        gload_lds16(gA + (long)(128 + r0) * lda + (kt_) * 32 + s0 * 8, (base_) + 8192 + tid * 16); \
    } while (0)
#define STG_B(base_, kt_)                                                                          \
    do {                                                                                           \
        gload_lds16(gB + (long)r0 * ldb + (kt_) * 32 + s0 * 8, (base_) + 16384 + tid * 16);        \
    } while (0)

    const int fr = lane & 15;
    const int kg3 = lane >> 4;

#define LD_A(dst, base_, mi_)                                                             \
    do {                                                                                  \
        const int row_ = wm * 64 + (mi_) * 16 + fr;                                       \
        const int sl_ = kg3 ^ (row_ & 3);                                                 \
        dst = *(const bf16x8*)((base_) + row_ * 64 + sl_ * 16);                           \
    } while (0)
#define LD_B(dst, base_, ni_)                                                             \
    do {                                                                                  \
        const int row_ = wn * 64 + (ni_) * 16 + fr;                                       \
        const int sl_ = kg3 ^ (row_ & 3);                                                 \
        dst = *(const bf16x8*)((base_) + 16384 + row_ * 64 + sl_ * 16);                   \
    } while (0)

    f32x4 acc[4][4];
#pragma unroll
    for (int mi = 0; mi < 4; ++mi)
#pragma unroll
        for (int ni = 0; ni < 4; ++ni) acc[mi][ni] = {0.f, 0.f, 0.f, 0.f};

    const int NT = K >> 5;

    STG_A(smem, 0); STG_B(smem, 0);
    STG_A(smem + 24576, 1); STG_B(smem + 24576, 1);
    WAITV(3);
    SYNC();

    int bi = 0;
    for (int t = 0; t < NT; ++t) {
        char* base = smem + bi * 24576;
        if (t + 2 < NT) {
            int bs = bi + 2; if (bs >= 3) bs -= 3;
            char* sb = smem + bs * 24576;
            STG_A(sb, t + 2); STG_B(sb, t + 2);
        }
        bf16x8 av[4], bv[4];
#pragma unroll
        for (int mi = 0; mi < 4; ++mi) LD_A(av[mi], base, mi);
#pragma unroll
        for (int ni = 0; ni < 4; ++ni) LD_B(bv[ni], base, ni);
        __builtin_amdgcn_s_setprio(1);
#pragma unroll
        for (int mi = 0; mi < 4; ++mi)
#pragma unroll
            for (int ni = 0; ni < 4; ++ni)
                acc[mi][ni] = __builtin_amdgcn_mfma_f32_16x16x32_bf16(av[mi], bv[ni], acc[mi][ni], 0, 0, 0);
        __builtin_amdgcn_s_setprio(0);
        if (t + 2 < NT) { WAITV(3); SYNC(); }
        else if (t + 1 < NT) { WAITV(0); SYNC(); }
        bi = (bi + 1 == 3) ? 0 : bi + 1;
    }

    const long row0 = (long)blockIdx.x * 256 + wm * 64 + (lane >> 4) * 4;
    const long col0 = (long)blockIdx.y * 128 + wn * 64 + (lane & 15);
    if (VOUT) {
        // rows = d, cols = (b,s); all 128 cols of this block are in one batch
#pragma unroll
        for (int mi = 0; mi < 4; ++mi) {
#pragma unroll
            for (int i = 0; i < 4; ++i) {
                const long row = row0 + mi * 16 + i;   // d
                const float bval = (bias != nullptr) ? bias[row] : 0.f;
#pragma unroll
                for (int ni = 0; ni < 4; ++ni) {
                    const long col = col0 + ni * 16;   // global (b,s)
                    const long vb = col >> 11;
                    const long vs = col & 2047;
                    vt[(vb << 21) + row * 2048 + vs] = __float2bfloat16(acc[mi][ni][i] + bval);
                }
            }
        }
    } else {
#pragma unroll
        for (int ni = 0; ni < 4; ++ni) {
            const long col = col0 + ni * 16;
            const float bval = (bias != nullptr) ? bias[col] : 0.f;
#pragma unroll
            for (int mi = 0; mi < 4; ++mi) {
                const long row = row0 + mi * 16;
#pragma unroll
                for (int i = 0; i < 4; ++i)
                    Cout[(long)b * strideC + (row + i) * (long)ldc + col] = __float2bfloat16(acc[mi][ni][i] + bval);
            }
        }
    }
#undef STG_A
#undef STG_B
#undef LD_A
#undef LD_B
}

// ---------------------------------------------------------------------------
// fused 6-way weight transpose: out[z][c][r] = (bf16) W_z[r][c]
// ---------------------------------------------------------------------------
__global__ __launch_bounds__(256) void transpose6(
    const float* __restrict__ W0, const float* __restrict__ W1, const float* __restrict__ W2,
    const float* __restrict__ W3, const float* __restrict__ W4, const float* __restrict__ W5,
    __hip_bfloat16* __restrict__ dst)
{
    __shared__ float tile[32][33];
    const int z = blockIdx.z;
    const float* pin = (z == 0) ? W0 : (z == 1) ? W1 : (z == 2) ? W2 : (z == 3) ? W3 : (z == 4) ? W4 : W5;
    __hip_bfloat16* pout = dst + (long)z * 1024 * 1024;
    const int tx = threadIdx.x, ty = threadIdx.y;
    const int c0 = blockIdx.x * 32, r0 = blockIdx.y * 32;
#pragma unroll
    for (int j = 0; j < 4; ++j)
        tile[ty + j * 8][tx] = pin[(long)(r0 + ty + j * 8) * 1024 + c0 + tx];
    __syncthreads();
#pragma unroll
    for (int j = 0; j < 4; ++j)
        pout[(long)(c0 + ty + j * 8) * 1024 + r0 + tx] = __float2bfloat16(tile[tx][ty + j * 8]);
}

// ---------------------------------------------------------------------------
__global__ __launch_bounds__(256) void f32_to_bf16_vec(
    const float* __restrict__ in, __hip_bfloat16* __restrict__ out, long n4)
{
    const long i = (long)blockIdx.x * 256 + threadIdx.x;
    if (i >= n4) return;
    const float4 v = ((const float4*)in)[i];
    union { __hip_bfloat16 h[4]; ushort4 u; } cv;
    cv.h[0] = __float2bfloat16(v.x);
    cv.h[1] = __float2bfloat16(v.y);
    cv.h[2] = __float2bfloat16(v.z);
    cv.h[3] = __float2bfloat16(v.w);
    ((ushort4*)out)[i] = cv.u;
}

// ---------------------------------------------------------------------------
__global__ __launch_bounds__(256) void concat_bias(
    const float* __restrict__ bq, const float* __restrict__ bk, const float* __restrict__ bv,
    const float* __restrict__ bo, const float* __restrict__ bgv, const float* __restrict__ bgg,
    float* __restrict__ out)
{
    const int i = blockIdx.x * 256 + threadIdx.x;  // 6144 total
    float v;
    if (i < 1024) v = bq[i];
    else if (i < 2048) v = bk[i - 1024];
    else if (i < 3072) v = bv[i - 2048];
    else if (i < 4096) v = bo[i - 3072];
    else if (i < 5120) v = bgv[i - 4096];
    else v = bgg[i - 5120];
    out[i] = v;
}

// ---------------------------------------------------------------------------
// row softmax: bf16 scores row (2048) -> bf16 probs
// ---------------------------------------------------------------------------
__global__ __launch_bounds__(256) void softmax_kernel(
    const __hip_bfloat16* __restrict__ S, __hip_bfloat16* __restrict__ P)
{
    const long row = blockIdx.x;
    const __hip_bfloat16* s = S + row * 2048;
    __hip_bfloat16* p = P + row * 2048;
    const int t = threadIdx.x;
    const bf16x8 v8 = *(const bf16x8*)(s + t * 8);
    float v[8];
    float mx = -1e30f;
#pragma unroll
    for (int j = 0; j < 8; ++j) { v[j] = (float)v8[j]; mx = fmaxf(mx, v[j]); }
#pragma unroll
    for (int off = 32; off; off >>= 1) mx = fmaxf(mx, __shfl_xor(mx, off));
    __shared__ float wred[4];
    __shared__ float wsum[4];
    const int w = t >> 6;
    if ((t & 63) == 0) wred[w] = mx;
    __syncthreads();
    mx = fmaxf(fmaxf(wred[0], wred[1]), fmaxf(wred[2], wred[3]));
    float sum = 0.f;
#pragma unroll
    for (int j = 0; j < 8; ++j) { v[j] = __expf(v[j] - mx); sum += v[j]; }
#pragma unroll
    for (int off = 32; off; off >>= 1) sum += __shfl_xor(sum, off);
    if ((t & 63) == 0) wsum[w] = sum;
    __syncthreads();
    sum = wsum[0] + wsum[1] + wsum[2] + wsum[3];
    const float inv = 1.0f / sum;
    bf16x8 o8;
#pragma unroll
    for (int j = 0; j < 8; ++j) o8[j] = (__bf16)(v[j] * inv);
    *(bf16x8*)(p + t * 8) = o8;
}

// ---------------------------------------------------------------------------
// T1G: bf16 [row][3072] = [T1 | Gval | Ggate]. y = T1 + Gv*sigmoid(Gg);
// out = LN(y)*gamma + beta (f32). One block per row.
// ---------------------------------------------------------------------------
__global__ __launch_bounds__(256) void glu_ln_kernel(
    const __hip_bfloat16* __restrict__ T1G,
    const float* __restrict__ gamma, const float* __restrict__ beta, float* __restrict__ out)
{
    const long row = blockIdx.x;
    const __hip_bfloat16* pr = T1G + row * 3072;
    const int t = threadIdx.x;
    const int c0 = t * 4;
    const bf16x4 t1 = *(const bf16x4*)(pr + c0);
    const bf16x4 gv = *(const bf16x4*)(pr + 1024 + c0);
    const bf16x4 gg = *(const bf16x4*)(pr + 2048 + c0);
    float y[4];
    float s = 0.f, ss = 0.f;
#pragma unroll
    for (int j = 0; j < 4; ++j) {
        const float g = (float)gv[j] * (1.0f / (1.0f + __expf(-(float)gg[j])));
        const float val = (float)t1[j] + g;
        y[j] = val; s += val; ss += val * val;
    }
#pragma unroll
    for (int off = 32; off; off >>= 1) { s += __shfl_xor(s, off); ss += __shfl_xor(ss, off); }
    __shared__ float rs[4], rss[4];
    const int w = t >> 6;
    if ((t & 63) == 0) { rs[w] = s; rss[w] = ss; }
    __syncthreads();
    s = rs[0] + rs[1] + rs[2] + rs[3];
    ss = rss[0] + rss[1] + rss[2] + rss[3];
    const float mu = s * (1.0f / 1024.0f);
    const float var = ss * (1.0f / 1024.0f) - mu * mu;
    const float r = rsqrtf(var + 1e-5f);
    const float4 gm = *(const float4*)(gamma + c0);
    const float4 bt = *(const float4*)(beta + c0);
    float4 o;
    o.x = (y[0] - mu) * r * gm.x + bt.x;
    o.y = (y[1] - mu) * r * gm.y + bt.y;
    o.z = (y[2] - mu) * r * gm.z + bt.z;
    o.w = (y[3] - mu) * r * gm.w + bt.w;
    *(float4*)(out + row * 1024 + c0) = o;
}

// ---------------------------------------------------------------------------
extern "C" void kernel_launch(void* const* d_in, const int* in_sizes, int n_in,
                              void* d_out, int out_size, void* d_ws, size_t ws_size,
                              hipStream_t stream)
{
    const int B = 4, S = 2048, D = 1024;
    const float* x    = (const float*)d_in[0];
    const float* Wq   = (const float*)d_in[1];
    const float* bq   = (const float*)d_in[2];
    const float* Wk   = (const float*)d_in[3];
    const float* bk   = (const float*)d_in[4];
    const float* Wv   = (const float*)d_in[5];
    const float* bv   = (const float*)d_in[6];
    const float* Wo   = (const float*)d_in[7];
    const float* bo   = (const float*)d_in[8];
    const float* Wgv  = (const float*)d_in[9];
    const float* bgv  = (const float*)d_in[10];
    const float* Wgg  = (const float*)d_in[11];
    const float* bgg  = (const float*)d_in[12];
    const float* gamma = (const float*)d_in[13];
    const float* beta  = (const float*)d_in[14];
    float* out = (float*)d_out;

    char* ws = (char*)d_ws;
    size_t off = 0;
    auto take = [&](size_t bytes) { char* p = ws + off; off += (bytes + 255) & ~(size_t)255; return p; };

    __hip_bfloat16* wcat   = (__hip_bfloat16*)take((size_t)6 * D * D * 2);  // [6][D][D]: Wq,Wk,Wv,Wo,Wgv,Wgg ^T
    float*          bcat   = (float*)take((size_t)6 * D * 4);
    __hip_bfloat16* xb     = (__hip_bfloat16*)take((size_t)B * S * D * 2);
    __hip_bfloat16* QKb    = (__hip_bfloat16*)take((size_t)B * S * 2 * D * 2); // [B*S][2D]: Q,K
    __hip_bfloat16* Vtb    = (__hip_bfloat16*)take((size_t)B * S * D * 2);     // [B][D][S]
    __hip_bfloat16* scoresb = (__hip_bfloat16*)take((size_t)B * S * S * 2);
    __hip_bfloat16* Pb     = (__hip_bfloat16*)take((size_t)B * S * S * 2);
    __hip_bfloat16* Oatt   = (__hip_bfloat16*)take((size_t)B * S * D * 2);
    __hip_bfloat16* T1G    = (__hip_bfloat16*)take((size_t)B * S * 3 * D * 2);

    const long SD = (long)S * D, SS = (long)S * S, S2D = (long)S * 2 * D;
    const float att_scale = 0.03125f;  // 1/sqrt(1024)
    const __hip_bfloat16* Qb = QKb;
    const __hip_bfloat16* Kb = QKb + D;

    // 1. prep: cast x, fused weight transposes, bias concat
    f32_to_bf16_vec<<<dim3((unsigned)((long)B * S * D / 4 / 256)), dim3(256), 0, stream>>>(x, xb, (long)B * S * D / 4);
    transpose6<<<dim3(D / 32, D / 32, 6), dim3(32, 8), 0, stream>>>(Wq, Wk, Wv, Wo, Wgv, Wgg, wcat);
    concat_bias<<<dim3(24), dim3(256), 0, stream>>>(bq, bk, bv, bo, bgv, bgg, bcat);

    // 2a. QKV_A: Q,K projection -> QKb [8192][2048]  (32x8 = 256 blocks)
    gemm256<0><<<dim3(B * S / 256, 2 * D / 256, 1), dim3(512), 0, stream>>>(
        xb, D, xb, D, 1 << 30, wcat, QKb, bcat, 1.f,
        D, D, 2 * D, 0, 0, 0);

    // 2b. Vproj: Vt = WvT @ x^T (swapped operands) -> Vtb [B][D][S]  (4x64 = 256 blocks)
    gemm_tn128<1><<<dim3(D / 256, B * S / 128, 1), dim3(512), 0, stream>>>(
        wcat + (size_t)2 * D * D, D, xb, nullptr, bcat + 2 * D, Vtb,
        D, D, 0, 0, 0, 0);

    // 3. scores = scale * Q K^T (bf16), per batch  (8x8x4 = 256 blocks)
    gemm256<1><<<dim3(S / 256, S / 256, B), dim3(512), 0, stream>>>(
        Qb, 2 * D, Qb, 2 * D, 1 << 30, Kb, scoresb, nullptr, att_scale,
        D, 2 * D, S, S2D, S2D, SS);

    // 4. row softmax -> bf16 P
    softmax_kernel<<<dim3(B * S), dim3(256), 0, stream>>>(scoresb, Pb);

    // 5. Oatt = P @ V  (8x8x4 = 256 blocks)
    gemm_tn128<0><<<dim3(S / 256, D / 128, B), dim3(512), 0, stream>>>(
        Pb, S, Vtb, Oatt, nullptr, nullptr, S, S, D, SS, SD, SD);

    // 6a. WoGLU_A: [T1 | Gval] -> T1G cols 0-2047 (A-select at col 1024)  (256 blocks)
    gemm256<0><<<dim3(B * S / 256, 2 * D / 256, 1), dim3(512), 0, stream>>>(
        Oatt, D, QKb, 2 * D, D, wcat + (size_t)3 * D * D, T1G, bcat + 3 * D, 1.f,
        D, D, 3 * D, 0, 0, 0);

    // 6b. WoGLU_B: Ggate = Q @ Wgg -> T1G cols 2048-3071  (32x8 = 256 blocks)
    gemm_tn128<0><<<dim3(B * S / 256, D / 128, 1), dim3(512), 0, stream>>>(
        QKb, 2 * D, wcat + (size_t)5 * D * D, T1G + 2 * D, bcat + 5 * D, nullptr,
        D, D, 3 * D, 0, 0, 0);

    // 7. y = T1 + Gval*sigmoid(Ggate); out = LayerNorm(y)*gamma+beta
    glu_ln_kernel<<<dim3(B * S), dim3(256), 0, stream>>>(T1G, gamma, beta, out);
}

// Round 13
// 225.990 us; speedup vs baseline: 4.2500x; 4.2500x over previous
//
#include <hip/hip_runtime.h>
#include <hip/hip_bf16.h>
#include <cstdint>

// ---------------------------------------------------------------------------
// SelfAttention fused block: B=4, S=2048, D=1024, fp32 in/out.
// R9: R11 revert (BK=64 everywhere, launch_bounds(512,1)) + gemm256_dual:
// Vproj (Vt = WvT x^T, swapped operands) and Ggate (Q Wgg^T) share ONE
// 256-block dispatch (128+128), replacing two half-efficiency tn128 rounds.
// Dispatches: QKV_A gemm256 | dual{Vt,Ggate} | scores gemm256 | softmax |
// PV tn128 | WoGLU_A gemm256+Asel | glu_ln.
// ---------------------------------------------------------------------------

typedef __bf16 bf16x8 __attribute__((ext_vector_type(8)));
typedef __bf16 bf16x4 __attribute__((ext_vector_type(4)));
typedef float f32x4 __attribute__((ext_vector_type(4)));

#define SYNC() do { asm volatile("" ::: "memory"); __builtin_amdgcn_s_barrier(); asm volatile("" ::: "memory"); } while (0)
#define WAITV(n) asm volatile("s_waitcnt vmcnt(" #n ")" ::: "memory")

__device__ __forceinline__ void gload_lds16(const void* g, void* l) {
    __builtin_amdgcn_global_load_lds(
        (__attribute__((address_space(1))) void*)(uintptr_t)g,
        (__attribute__((address_space(3))) void*)(uintptr_t)l,
        16, 0, 0);
}

// common macro set for the 256x256 BK=64 body (expects locals:
// smem, gA, gB, lda, ldb, tid, lane, wm, wn, r0, s0, r1, s1, fr, kg)
#define STAGE(buf, isB, half, kt)                                                        \
    do {                                                                                 \
        const __hip_bfloat16* g_ = (isB) ? gB : gA;                                      \
        const int ld_ = (isB) ? ldb : lda;                                               \
        char* l_ = smem + (buf) * 65536 + (isB) * 32768 + (half) * 16384;                \
        gload_lds16(g_ + (long)((half) * 128 + r0) * ld_ + (kt) * 64 + s0 * 8, l_ + tid * 16);        \
        gload_lds16(g_ + (long)((half) * 128 + r1) * ld_ + (kt) * 64 + s1 * 8, l_ + 8192 + tid * 16); \
    } while (0)
#define LDA_(dst, buf, mh, mi, kk)                                                       \
    do {                                                                                 \
        const int lr_ = wm * 64 + (mi) * 16 + fr;                                        \
        const int sl_ = ((kk) * 4 + kg) ^ (lr_ & 7);                                     \
        dst = *(const bf16x8*)(smem + (buf) * 65536 + (mh) * 16384 + lr_ * 128 + sl_ * 16); \
    } while (0)
#define LDB_(dst, buf, nh, ni, kk)                                                       \
    do {                                                                                 \
        const int lr_ = wn * 32 + (ni) * 16 + fr;                                        \
        const int sl_ = ((kk) * 4 + kg) ^ (lr_ & 7);                                     \
        dst = *(const bf16x8*)(smem + (buf) * 65536 + 32768 + (nh) * 16384 + lr_ * 128 + sl_ * 16); \
    } while (0)
#define MFMA_QUAD(mh, nh)                                                                \
    do {                                                                                 \
        __builtin_amdgcn_s_setprio(1);                                                   \
        _Pragma("unroll")                                                                \
        for (int mi = 0; mi < 4; ++mi)                                                   \
            _Pragma("unroll")                                                            \
            for (int ni = 0; ni < 2; ++ni)                                               \
                _Pragma("unroll")                                                        \
                for (int kk = 0; kk < 2; ++kk)                                           \
                    acc[mh][nh][mi][ni] = __builtin_amdgcn_mfma_f32_16x16x32_bf16(       \
                        av[mi][kk], bv[ni][kk], acc[mh][nh][mi][ni], 0, 0, 0);           \
        __builtin_amdgcn_s_setprio(0);                                                   \
    } while (0)

// main loop: 4 phases/K-tile, counted vmcnt(4); prologue+peel (R2-proven).
#define GEMM256_BODY(NT)                                                                 \
    STAGE(0, 0, 0, 0);                                                                   \
    STAGE(0, 1, 0, 0);                                                                   \
    STAGE(0, 1, 1, 0);                                                                   \
    STAGE(0, 0, 1, 0);                                                                   \
    WAITV(4);                                                                            \
    SYNC();                                                                              \
    for (int t = 0; t < (NT) - 1; ++t) {                                                 \
        const int c = t & 1;                                                             \
        _Pragma("unroll")                                                                \
        for (int mi = 0; mi < 4; ++mi) { LDA_(av[mi][0], c, 0, mi, 0); LDA_(av[mi][1], c, 0, mi, 1); } \
        _Pragma("unroll")                                                                \
        for (int ni = 0; ni < 2; ++ni) { LDB_(bv[ni][0], c, 0, ni, 0); LDB_(bv[ni][1], c, 0, ni, 1); } \
        STAGE(c ^ 1, 0, 0, t + 1);                                                       \
        MFMA_QUAD(0, 0);                                                                 \
        WAITV(4);                                                                        \
        SYNC();                                                                          \
        _Pragma("unroll")                                                                \
        for (int ni = 0; ni < 2; ++ni) { LDB_(bv[ni][0], c, 1, ni, 0); LDB_(bv[ni][1], c, 1, ni, 1); } \
        STAGE(c ^ 1, 1, 0, t + 1);                                                       \
        MFMA_QUAD(0, 1);                                                                 \
        WAITV(4);                                                                        \
        SYNC();                                                                          \
        _Pragma("unroll")                                                                \
        for (int mi = 0; mi < 4; ++mi) { LDA_(av[mi][0], c, 1, mi, 0); LDA_(av[mi][1], c, 1, mi, 1); } \
        STAGE(c ^ 1, 1, 1, t + 1);                                                       \
        MFMA_QUAD(1, 1);                                                                 \
        SYNC();                                                                          \
        _Pragma("unroll")                                                                \
        for (int ni = 0; ni < 2; ++ni) { LDB_(bv[ni][0], c, 0, ni, 0); LDB_(bv[ni][1], c, 0, ni, 1); } \
        STAGE(c ^ 1, 0, 1, t + 1);                                                       \
        MFMA_QUAD(1, 0);                                                                 \
        WAITV(4);                                                                        \
        SYNC();                                                                          \
    }                                                                                    \
    {                                                                                    \
        const int c = ((NT) - 1) & 1;                                                    \
        _Pragma("unroll")                                                                \
        for (int mi = 0; mi < 4; ++mi) { LDA_(av[mi][0], c, 0, mi, 0); LDA_(av[mi][1], c, 0, mi, 1); } \
        _Pragma("unroll")                                                                \
        for (int ni = 0; ni < 2; ++ni) { LDB_(bv[ni][0], c, 0, ni, 0); LDB_(bv[ni][1], c, 0, ni, 1); } \
        MFMA_QUAD(0, 0);                                                                 \
        WAITV(2);                                                                        \
        SYNC();                                                                          \
        _Pragma("unroll")                                                                \
        for (int ni = 0; ni < 2; ++ni) { LDB_(bv[ni][0], c, 1, ni, 0); LDB_(bv[ni][1], c, 1, ni, 1); } \
        MFMA_QUAD(0, 1);                                                                 \
        WAITV(0);                                                                        \
        SYNC();                                                                          \
        _Pragma("unroll")                                                                \
        for (int mi = 0; mi < 4; ++mi) { LDA_(av[mi][0], c, 1, mi, 0); LDA_(av[mi][1], c, 1, mi, 1); } \
        MFMA_QUAD(1, 1);                                                                 \
        _Pragma("unroll")                                                                \
        for (int ni = 0; ni < 2; ++ni) { LDB_(bv[ni][0], c, 0, ni, 0); LDB_(bv[ni][1], c, 0, ni, 1); } \
        MFMA_QUAD(1, 0);                                                                 \
    }

// ---------------------------------------------------------------------------
// gemm256: C[m,n] = sum_k A[m,k] * Bt[n,k].  Tile 256x256, BK=64, 8 waves.
// EPI 0: bf16 = acc + bias; EPI 1: bf16 = acc * scale.
// A-select: blockIdx.y*256 >= nsplit -> A2/lda2.
// ---------------------------------------------------------------------------
template <int EPI>
__global__ __launch_bounds__(512, 1) void gemm256(
    const __hip_bfloat16* __restrict__ A1, int lda1,
    const __hip_bfloat16* __restrict__ A2, int lda2, int nsplit,
    const __hip_bfloat16* __restrict__ Bt,
    __hip_bfloat16* __restrict__ Cout, const float* __restrict__ bias, float scale,
    int K, int ldb, int ldc,
    long strideA, long strideB, long strideC)
{
    __shared__ __align__(16) char smem[131072];

    const int b = blockIdx.z;
    const int tid = threadIdx.x;
    const int lane = tid & 63;
    const int wm = (tid >> 6) & 1;
    const int wn = (tid >> 6) >> 1;

    const bool sel2 = ((int)blockIdx.y * 256) >= nsplit;
    const __hip_bfloat16* A = sel2 ? A2 : A1;
    const int lda = sel2 ? lda2 : lda1;

    const __hip_bfloat16* gA = A + (long)b * strideA + (long)blockIdx.x * 256 * lda;
    const __hip_bfloat16* gB = Bt + (long)b * strideB + (long)blockIdx.y * 256 * ldb;

    const int r0 = tid >> 3;
    const int s0 = (tid & 7) ^ (r0 & 7);
    const int r1 = r0 + 64;
    const int s1 = (tid & 7) ^ (r1 & 7);
    const int fr = lane & 15;
    const int kg = lane >> 4;

    f32x4 acc[2][2][4][2];
#pragma unroll
    for (int mh = 0; mh < 2; ++mh)
#pragma unroll
        for (int nh = 0; nh < 2; ++nh)
#pragma unroll
            for (int mi = 0; mi < 4; ++mi)
#pragma unroll
                for (int ni = 0; ni < 2; ++ni) acc[mh][nh][mi][ni] = {0.f, 0.f, 0.f, 0.f};
    bf16x8 av[4][2], bv[2][2];

    const int NT = K >> 6;
    GEMM256_BODY(NT)

    const long row0 = (long)blockIdx.x * 256 + wm * 64 + (lane >> 4) * 4;
    const long col0 = (long)blockIdx.y * 256 + wn * 32 + (lane & 15);
#pragma unroll
    for (int mh = 0; mh < 2; ++mh) {
#pragma unroll
        for (int nh = 0; nh < 2; ++nh) {
#pragma unroll
            for (int ni = 0; ni < 2; ++ni) {
                const long col = col0 + nh * 128 + ni * 16;
                const float bval = (EPI == 0 && bias != nullptr) ? bias[col] : 0.f;
#pragma unroll
                for (int mi = 0; mi < 4; ++mi) {
                    const long row = row0 + mh * 128 + mi * 16;
#pragma unroll
                    for (int i = 0; i < 4; ++i) {
                        const float v = (EPI == 1) ? acc[mh][nh][mi][ni][i] * scale
                                                   : acc[mh][nh][mi][ni][i] + bval;
                        Cout[(long)b * strideC + (row + i) * (long)ldc + col] = __float2bfloat16(v);
                    }
                }
            }
        }
    }
}

// ---------------------------------------------------------------------------
// gemm256_dual: one 256-block dispatch covering two K=1024 GEMMs.
//  bid<128 (Vt):   C[d][(b,s)] = sum_e WvT[d][e] xb[(b,s)][e] + bv[d]
//                  -> vt[b][d][s]   (grid 4x32 of 256x256 tiles)
//  bid>=128 (Gg):  C[(b,s)][g] = sum_e Q[(b,s)][e] WggT[g][e] + bgg[g]
//                  -> T1G[row][2048+g]  (grid 32x4)
// ---------------------------------------------------------------------------
__global__ __launch_bounds__(512, 1) void gemm256_dual(
    const __hip_bfloat16* __restrict__ wvT,   // [1024][1024]
    const __hip_bfloat16* __restrict__ xb,    // [8192][1024]
    const __hip_bfloat16* __restrict__ Qp,    // [8192][2048] (Q cols 0-1023)
    const __hip_bfloat16* __restrict__ wggT,  // [1024][1024]
    __hip_bfloat16* __restrict__ vt,          // [4][1024][2048]
    __hip_bfloat16* __restrict__ T1G,         // [8192][3072]
    const float* __restrict__ bv,             // [1024]
    const float* __restrict__ bgg)            // [1024]
{
    __shared__ __align__(16) char smem[131072];

    const int bid = blockIdx.x;
    const bool isVt = bid < 128;
    const int tid = threadIdx.x;
    const int lane = tid & 63;
    const int wm = (tid >> 6) & 1;
    const int wn = (tid >> 6) >> 1;

    int mx, my, lda, ldb;
    const __hip_bfloat16 *Aop, *Bop;
    if (isVt) { mx = bid >> 5; my = bid & 31; Aop = wvT; lda = 1024; Bop = xb;   ldb = 1024; }
    else { const int t2 = bid - 128; mx = t2 >> 2; my = t2 & 3; Aop = Qp; lda = 2048; Bop = wggT; ldb = 1024; }

    const __hip_bfloat16* gA = Aop + (long)mx * 256 * lda;
    const __hip_bfloat16* gB = Bop + (long)my * 256 * ldb;

    const int r0 = tid >> 3;
    const int s0 = (tid & 7) ^ (r0 & 7);
    const int r1 = r0 + 64;
    const int s1 = (tid & 7) ^ (r1 & 7);
    const int fr = lane & 15;
    const int kg = lane >> 4;

    f32x4 acc[2][2][4][2];
#pragma unroll
    for (int mh = 0; mh < 2; ++mh)
#pragma unroll
        for (int nh = 0; nh < 2; ++nh)
#pragma unroll
            for (int mi = 0; mi < 4; ++mi)
#pragma unroll
                for (int ni = 0; ni < 2; ++ni) acc[mh][nh][mi][ni] = {0.f, 0.f, 0.f, 0.f};
    bf16x8 av[4][2], bv2[2][2];
    // rename for macro compatibility
    #define bv bv2
    GEMM256_BODY(16)
    #undef bv

    const long row0 = (long)mx * 256 + wm * 64 + (lane >> 4) * 4;
    const long col0 = (long)my * 256 + wn * 32 + (lane & 15);
    if (isVt) {
#pragma unroll
        for (int mh = 0; mh < 2; ++mh)
#pragma unroll
            for (int nh = 0; nh < 2; ++nh)
#pragma unroll
                for (int ni = 0; ni < 2; ++ni) {
                    const long col = col0 + nh * 128 + ni * 16;   // global (b,s)
                    const long vb = col >> 11, vs = col & 2047;
#pragma unroll
                    for (int mi = 0; mi < 4; ++mi) {
#pragma unroll
                        for (int i = 0; i < 4; ++i) {
                            const long row = row0 + mh * 128 + mi * 16 + i;  // d
                            vt[(vb << 21) + row * 2048 + vs] =
                                __float2bfloat16(acc[mh][nh][mi][ni][i] + bv[row]);
                        }
                    }
                }
    } else {
#pragma unroll
        for (int mh = 0; mh < 2; ++mh)
#pragma unroll
            for (int nh = 0; nh < 2; ++nh)
#pragma unroll
                for (int ni = 0; ni < 2; ++ni) {
                    const long col = col0 + nh * 128 + ni * 16;   // gate col
                    const float bval = bgg[col];
#pragma unroll
                    for (int mi = 0; mi < 4; ++mi) {
                        const long row = row0 + mh * 128 + mi * 16;
#pragma unroll
                        for (int i = 0; i < 4; ++i)
                            T1G[(row + i) * 3072 + 2048 + col] =
                                __float2bfloat16(acc[mh][nh][mi][ni][i] + bval);
                    }
                }
    }
}

// ---------------------------------------------------------------------------
// gemm_tn128 (PV): 256x128, BK=64, triple-buffer, ONE barrier per K-tile,
// counted WAITV(6) at tile boundary (R3-proven coarse schedule).
// ---------------------------------------------------------------------------
__global__ __launch_bounds__(512, 1) void gemm_tn128(
    const __hip_bfloat16* __restrict__ A, int lda,
    const __hip_bfloat16* __restrict__ Bt,
    __hip_bfloat16* __restrict__ Cout, const float* __restrict__ bias,
    int K, int ldb, int ldc,
    long strideA, long strideB, long strideC)
{
    __shared__ __align__(16) char smem[147456];   // 3 x 49152

    const int b = blockIdx.z;
    const int tid = threadIdx.x;
    const int lane = tid & 63;
    const int wid = tid >> 6;
    const int wm = wid & 3;
    const int wn = wid >> 2;

    const __hip_bfloat16* gA = A + (long)b * strideA + (long)blockIdx.x * 256 * lda;
    const __hip_bfloat16* gB = Bt + (long)b * strideB + (long)blockIdx.y * 128 * ldb;

    const int r0 = tid >> 3, r1 = r0 + 64;
    const int s0 = (tid & 7) ^ (r0 & 7);
    const int s1 = (tid & 7) ^ (r1 & 7);

#define STG_A(base_, h_, kt_)                                                                              \
    do {                                                                                                   \
        gload_lds16(gA + (long)((h_) * 128 + r0) * lda + (kt_) * 64 + s0 * 8, (base_) + (h_) * 16384 + tid * 16);        \
        gload_lds16(gA + (long)((h_) * 128 + r1) * lda + (kt_) * 64 + s1 * 8, (base_) + (h_) * 16384 + 8192 + tid * 16); \
    } while (0)
#define STG_B(base_, kt_)                                                                                  \
    do {                                                                                                   \
        gload_lds16(gB + (long)r0 * ldb + (kt_) * 64 + s0 * 8, (base_) + 32768 + tid * 16);                \
        gload_lds16(gB + (long)r1 * ldb + (kt_) * 64 + s1 * 8, (base_) + 32768 + 8192 + tid * 16);         \
    } while (0)

    const int fr = lane & 15;
    const int kg = lane >> 4;

#define LD_A(dst, base_, mi_, kk_)                                                        \
    do {                                                                                  \
        const int row_ = wm * 64 + (mi_) * 16 + fr;                                       \
        const int sl_ = ((kk_) * 4 + kg) ^ (row_ & 7);                                    \
        dst = *(const bf16x8*)((base_) + row_ * 128 + sl_ * 16);                          \
    } while (0)
#define LD_B(dst, base_, ni_, kk_)                                                        \
    do {                                                                                  \
        const int row_ = wn * 64 + (ni_) * 16 + fr;                                       \
        const int sl_ = ((kk_) * 4 + kg) ^ (row_ & 7);                                    \
        dst = *(const bf16x8*)((base_) + 32768 + row_ * 128 + sl_ * 16);                  \
    } while (0)

    f32x4 acc[4][4];
#pragma unroll
    for (int mi = 0; mi < 4; ++mi)
#pragma unroll
        for (int ni = 0; ni < 4; ++ni) acc[mi][ni] = {0.f, 0.f, 0.f, 0.f};

    const int NT = K >> 6;

    STG_A(smem, 0, 0); STG_A(smem, 1, 0); STG_B(smem, 0);
    STG_A(smem + 49152, 0, 1); STG_A(smem + 49152, 1, 1); STG_B(smem + 49152, 1);
    WAITV(6);
    SYNC();

    int bi = 0;
    for (int t = 0; t < NT; ++t) {
        char* base = smem + bi * 49152;
        if (t + 2 < NT) {
            int bs = bi + 2; if (bs >= 3) bs -= 3;
            char* sb = smem + bs * 49152;
            STG_A(sb, 0, t + 2); STG_A(sb, 1, t + 2); STG_B(sb, t + 2);
        }
        bf16x8 av[4], bvv[4];
#pragma unroll
        for (int kk = 0; kk < 2; ++kk) {
#pragma unroll
            for (int mi = 0; mi < 4; ++mi) LD_A(av[mi], base, mi, kk);
#pragma unroll
            for (int ni = 0; ni < 4; ++ni) LD_B(bvv[ni], base, ni, kk);
            __builtin_amdgcn_s_setprio(1);
#pragma unroll
            for (int mi = 0; mi < 4; ++mi)
#pragma unroll
                for (int ni = 0; ni < 4; ++ni)
                    acc[mi][ni] = __builtin_amdgcn_mfma_f32_16x16x32_bf16(av[mi], bvv[ni], acc[mi][ni], 0, 0, 0);
            __builtin_amdgcn_s_setprio(0);
        }
        if (t + 2 < NT) { WAITV(6); SYNC(); }
        else if (t + 1 < NT) { WAITV(0); SYNC(); }
        bi = (bi + 1 == 3) ? 0 : bi + 1;
    }

    const long row0 = (long)blockIdx.x * 256 + wm * 64 + (lane >> 4) * 4;
    const long col0 = (long)blockIdx.y * 128 + wn * 64 + (lane & 15);
#pragma unroll
    for (int ni = 0; ni < 4; ++ni) {
        const long col = col0 + ni * 16;
        const float bval = (bias != nullptr) ? bias[col] : 0.f;
#pragma unroll
        for (int mi = 0; mi < 4; ++mi) {
            const long row = row0 + mi * 16;
#pragma unroll
            for (int i = 0; i < 4; ++i)
                Cout[(long)b * strideC + (row + i) * (long)ldc + col] = __float2bfloat16(acc[mi][ni][i] + bval);
        }
    }
#undef STG_A
#undef STG_B
#undef LD_A
#undef LD_B
}

// ---------------------------------------------------------------------------
// fused 6-way weight transpose: out[z][c][r] = (bf16) W_z[r][c]
// ---------------------------------------------------------------------------
__global__ __launch_bounds__(256) void transpose6(
    const float* __restrict__ W0, const float* __restrict__ W1, const float* __restrict__ W2,
    const float* __restrict__ W3, const float* __restrict__ W4, const float* __restrict__ W5,
    __hip_bfloat16* __restrict__ dst)
{
    __shared__ float tile[32][33];
    const int z = blockIdx.z;
    const float* pin = (z == 0) ? W0 : (z == 1) ? W1 : (z == 2) ? W2 : (z == 3) ? W3 : (z == 4) ? W4 : W5;
    __hip_bfloat16* pout = dst + (long)z * 1024 * 1024;
    const int tx = threadIdx.x, ty = threadIdx.y;
    const int c0 = blockIdx.x * 32, r0 = blockIdx.y * 32;
#pragma unroll
    for (int j = 0; j < 4; ++j)
        tile[ty + j * 8][tx] = pin[(long)(r0 + ty + j * 8) * 1024 + c0 + tx];
    __syncthreads();
#pragma unroll
    for (int j = 0; j < 4; ++j)
        pout[(long)(c0 + ty + j * 8) * 1024 + r0 + tx] = __float2bfloat16(tile[tx][ty + j * 8]);
}

// ---------------------------------------------------------------------------
__global__ __launch_bounds__(256) void f32_to_bf16_vec(
    const float* __restrict__ in, __hip_bfloat16* __restrict__ out, long n4)
{
    const long i = (long)blockIdx.x * 256 + threadIdx.x;
    if (i >= n4) return;
    const float4 v = ((const float4*)in)[i];
    union { __hip_bfloat16 h[4]; ushort4 u; } cv;
    cv.h[0] = __float2bfloat16(v.x);
    cv.h[1] = __float2bfloat16(v.y);
    cv.h[2] = __float2bfloat16(v.z);
    cv.h[3] = __float2bfloat16(v.w);
    ((ushort4*)out)[i] = cv.u;
}

// ---------------------------------------------------------------------------
__global__ __launch_bounds__(256) void concat_bias(
    const float* __restrict__ bq, const float* __restrict__ bk, const float* __restrict__ bv,
    const float* __restrict__ bo, const float* __restrict__ bgv, const float* __restrict__ bgg,
    float* __restrict__ out)
{
    const int i = blockIdx.x * 256 + threadIdx.x;  // 6144 total
    float v;
    if (i < 1024) v = bq[i];
    else if (i < 2048) v = bk[i - 1024];
    else if (i < 3072) v = bv[i - 2048];
    else if (i < 4096) v = bo[i - 3072];
    else if (i < 5120) v = bgv[i - 4096];
    else v = bgg[i - 5120];
    out[i] = v;
}

// ---------------------------------------------------------------------------
// row softmax: bf16 scores row (2048) -> bf16 probs
// ---------------------------------------------------------------------------
__global__ __launch_bounds__(256) void softmax_kernel(
    const __hip_bfloat16* __restrict__ S, __hip_bfloat16* __restrict__ P)
{
    const long row = blockIdx.x;
    const __hip_bfloat16* s = S + row * 2048;
    __hip_bfloat16* p = P + row * 2048;
    const int t = threadIdx.x;
    const bf16x8 v8 = *(const bf16x8*)(s + t * 8);
    float v[8];
    float mx = -1e30f;
#pragma unroll
    for (int j = 0; j < 8; ++j) { v[j] = (float)v8[j]; mx = fmaxf(mx, v[j]); }
#pragma unroll
    for (int off = 32; off; off >>= 1) mx = fmaxf(mx, __shfl_xor(mx, off));
    __shared__ float wred[4];
    __shared__ float wsum[4];
    const int w = t >> 6;
    if ((t & 63) == 0) wred[w] = mx;
    __syncthreads();
    mx = fmaxf(fmaxf(wred[0], wred[1]), fmaxf(wred[2], wred[3]));
    float sum = 0.f;
#pragma unroll
    for (int j = 0; j < 8; ++j) { v[j] = __expf(v[j] - mx); sum += v[j]; }
#pragma unroll
    for (int off = 32; off; off >>= 1) sum += __shfl_xor(sum, off);
    if ((t & 63) == 0) wsum[w] = sum;
    __syncthreads();
    sum = wsum[0] + wsum[1] + wsum[2] + wsum[3];
    const float inv = 1.0f / sum;
    bf16x8 o8;
#pragma unroll
    for (int j = 0; j < 8; ++j) o8[j] = (__bf16)(v[j] * inv);
    *(bf16x8*)(p + t * 8) = o8;
}

// ---------------------------------------------------------------------------
// T1G: bf16 [row][3072] = [T1 | Gval | Ggate]. y = T1 + Gv*sigmoid(Gg);
// out = LN(y)*gamma + beta (f32). One block per row.
// ---------------------------------------------------------------------------
__global__ __launch_bounds__(256) void glu_ln_kernel(
    const __hip_bfloat16* __restrict__ T1G,
    const float* __restrict__ gamma, const float* __restrict__ beta, float* __restrict__ out)
{
    const long row = blockIdx.x;
    const __hip_bfloat16* pr = T1G + row * 3072;
    const int t = threadIdx.x;
    const int c0 = t * 4;
    const bf16x4 t1 = *(const bf16x4*)(pr + c0);
    const bf16x4 gv = *(const bf16x4*)(pr + 1024 + c0);
    const bf16x4 gg = *(const bf16x4*)(pr + 2048 + c0);
    float y[4];
    float s = 0.f, ss = 0.f;
#pragma unroll
    for (int j = 0; j < 4; ++j) {
        const float g = (float)gv[j] * (1.0f / (1.0f + __expf(-(float)gg[j])));
        const float val = (float)t1[j] + g;
        y[j] = val; s += val; ss += val * val;
    }
#pragma unroll
    for (int off = 32; off; off >>= 1) { s += __shfl_xor(s, off); ss += __shfl_xor(ss, off); }
    __shared__ float rs[4], rss[4];
    const int w = t >> 6;
    if ((t & 63) == 0) { rs[w] = s; rss[w] = ss; }
    __syncthreads();
    s = rs[0] + rs[1] + rs[2] + rs[3];
    ss = rss[0] + rss[1] + rss[2] + rss[3];
    const float mu = s * (1.0f / 1024.0f);
    const float var = ss * (1.0f / 1024.0f) - mu * mu;
    const float r = rsqrtf(var + 1e-5f);
    const float4 gm = *(const float4*)(gamma + c0);
    const float4 bt = *(const float4*)(beta + c0);
    float4 o;
    o.x = (y[0] - mu) * r * gm.x + bt.x;
    o.y = (y[1] - mu) * r * gm.y + bt.y;
    o.z = (y[2] - mu) * r * gm.z + bt.z;
    o.w = (y[3] - mu) * r * gm.w + bt.w;
    *(float4*)(out + row * 1024 + c0) = o;
}

// ---------------------------------------------------------------------------
extern "C" void kernel_launch(void* const* d_in, const int* in_sizes, int n_in,
                              void* d_out, int out_size, void* d_ws, size_t ws_size,
                              hipStream_t stream)
{
    const int B = 4, S = 2048, D = 1024;
    const float* x    = (const float*)d_in[0];
    const float* Wq   = (const float*)d_in[1];
    const float* bq   = (const float*)d_in[2];
    const float* Wk   = (const float*)d_in[3];
    const float* bk   = (const float*)d_in[4];
    const float* Wv   = (const float*)d_in[5];
    const float* bv   = (const float*)d_in[6];
    const float* Wo   = (const float*)d_in[7];
    const float* bo   = (const float*)d_in[8];
    const float* Wgv  = (const float*)d_in[9];
    const float* bgv  = (const float*)d_in[10];
    const float* Wgg  = (const float*)d_in[11];
    const float* bgg  = (const float*)d_in[12];
    const float* gamma = (const float*)d_in[13];
    const float* beta  = (const float*)d_in[14];
    float* out = (float*)d_out;

    char* ws = (char*)d_ws;
    size_t off = 0;
    auto take = [&](size_t bytes) { char* p = ws + off; off += (bytes + 255) & ~(size_t)255; return p; };

    __hip_bfloat16* wcat   = (__hip_bfloat16*)take((size_t)6 * D * D * 2);  // [6][D][D]: Wq,Wk,Wv,Wo,Wgv,Wgg ^T
    float*          bcat   = (float*)take((size_t)6 * D * 4);
    __hip_bfloat16* xb     = (__hip_bfloat16*)take((size_t)B * S * D * 2);
    __hip_bfloat16* QKb    = (__hip_bfloat16*)take((size_t)B * S * 2 * D * 2); // [B*S][2D]: Q,K
    __hip_bfloat16* Vtb    = (__hip_bfloat16*)take((size_t)B * S * D * 2);     // [B][D][S]
    __hip_bfloat16* scoresb = (__hip_bfloat16*)take((size_t)B * S * S * 2);
    __hip_bfloat16* Pb     = (__hip_bfloat16*)take((size_t)B * S * S * 2);
    __hip_bfloat16* Oatt   = (__hip_bfloat16*)take((size_t)B * S * D * 2);
    __hip_bfloat16* T1G    = (__hip_bfloat16*)take((size_t)B * S * 3 * D * 2);

    const long SD = (long)S * D, SS = (long)S * S, S2D = (long)S * 2 * D;
    const float att_scale = 0.03125f;  // 1/sqrt(1024)
    const __hip_bfloat16* Qb = QKb;
    const __hip_bfloat16* Kb = QKb + D;

    // 1. prep: cast x, fused weight transposes, bias concat
    f32_to_bf16_vec<<<dim3((unsigned)((long)B * S * D / 4 / 256)), dim3(256), 0, stream>>>(x, xb, (long)B * S * D / 4);
    transpose6<<<dim3(D / 32, D / 32, 6), dim3(32, 8), 0, stream>>>(Wq, Wk, Wv, Wo, Wgv, Wgg, wcat);
    concat_bias<<<dim3(24), dim3(256), 0, stream>>>(bq, bk, bv, bo, bgv, bgg, bcat);

    // 2. QKV_A: Q,K projection -> QKb [8192][2048]  (32x8 = 256 blocks)
    gemm256<0><<<dim3(B * S / 256, 2 * D / 256, 1), dim3(512), 0, stream>>>(
        xb, D, xb, D, 1 << 30, wcat, QKb, bcat, 1.f,
        D, D, 2 * D, 0, 0, 0);

    // 3. dual: Vt = WvT @ xb^T -> Vtb  +  Ggate = Q @ WggT -> T1G cols 2048+
    //    (128 + 128 = 256 blocks, one round)
    gemm256_dual<<<dim3(256), dim3(512), 0, stream>>>(
        wcat + (size_t)2 * D * D, xb, QKb, wcat + (size_t)5 * D * D,
        Vtb, T1G, bcat + 2 * D, bcat + 5 * D);

    // 4. scores = scale * Q K^T (bf16), per batch  (8x8x4 = 256 blocks)
    gemm256<1><<<dim3(S / 256, S / 256, B), dim3(512), 0, stream>>>(
        Qb, 2 * D, Qb, 2 * D, 1 << 30, Kb, scoresb, nullptr, att_scale,
        D, 2 * D, S, S2D, S2D, SS);

    // 5. row softmax -> bf16 P
    softmax_kernel<<<dim3(B * S), dim3(256), 0, stream>>>(scoresb, Pb);

    // 6. Oatt = P @ V  (8x8x4 = 256 blocks)
    gemm_tn128<<<dim3(S / 256, D / 128, B), dim3(512), 0, stream>>>(
        Pb, S, Vtb, Oatt, nullptr, S, S, D, SS, SD, SD);

    // 7. WoGLU_A: [T1 | Gval] -> T1G cols 0-2047 (A-select at col 1024)  (256 blocks)
    gemm256<0><<<dim3(B * S / 256, 2 * D / 256, 1), dim3(512), 0, stream>>>(
        Oatt, D, QKb, 2 * D, D, wcat + (size_t)3 * D * D, T1G, bcat + 3 * D, 1.f,
        D, D, 3 * D, 0, 0, 0);

    // 8. y = T1 + Gval*sigmoid(Ggate); out = LayerNorm(y)*gamma+beta
    glu_ln_kernel<<<dim3(B * S), dim3(256), 0, stream>>>(T1G, gamma, beta, out);
}